// Round 1
// baseline (1600.263 us; speedup 1.0000x reference)
//
#include <hip/hip_runtime.h>
#include <cstdint>
#include <cstddef>

#define T_TOK 4096
#define H_DIM 2048
#define I_DIM 4096
#define E_NUM 8
#define CAP_ROWS 9216   // max padded rows: 8192 + 8*127 = 9208, rounded up

// ---------------- workspace layout (bytes) ----------------
#define OFF_COUNTS   0                               // int[8]
#define OFF_CURSOR   64                              // int[8]
#define OFF_PADOFF   128                             // int[9]
#define OFF_TOKIDX   1024                            // int[CAP_ROWS]
#define OFF_TOKGATE  (OFF_TOKIDX + CAP_ROWS*4)       // float[CAP_ROWS]
#define OFF_XQ       ((size_t)(OFF_TOKGATE + CAP_ROWS*4))     // bf16[CAP][H]
#define XQ_BYTES     ((size_t)CAP_ROWS*H_DIM*2)
#define OFF_AQ       (OFF_XQ + XQ_BYTES)                       // bf16[CAP][I]
#define AQ_BYTES     ((size_t)CAP_ROWS*I_DIM*2)
#define OFF_W1B      (OFF_AQ + AQ_BYTES)                       // bf16[E][2I][H]
#define W1B_BYTES    ((size_t)E_NUM*2*I_DIM*H_DIM*2)
#define OFF_W2B      (OFF_W1B + W1B_BYTES)                     // bf16[E][H][I]

typedef __bf16 bf16x8 __attribute__((ext_vector_type(8)));
typedef float  f32x4  __attribute__((ext_vector_type(4)));

__device__ __forceinline__ unsigned short bf16hi(float f) {
  // exact for fp8-grid values (low mantissa bits are zero)
  return (unsigned short)(__float_as_uint(f) >> 16);
}

// RNE round of f32 to the fp8 e4m3fn grid (after clip to +-448), returned as f32.
__device__ __forceinline__ float fp8_round(float v) {
  v = fminf(448.f, fmaxf(-448.f, v));
  float av = fabsf(v);
  if (av < 0.015625f) {                 // below min normal 2^-6: subnormal grid, step 2^-9
    return rintf(v * 512.f) * (1.f / 512.f);
  }
  unsigned u = __float_as_uint(v);
  unsigned lsb = (u >> 20) & 1u;        // RNE to 3 mantissa bits
  u += 0x7FFFFu + lsb;
  u &= 0xFFF00000u;
  return __uint_as_float(u);
}

__device__ __forceinline__ void gld16(const void* g, void* l) {
  __builtin_amdgcn_global_load_lds(
      (__attribute__((address_space(1))) void*)((void*)g),
      (__attribute__((address_space(3))) void*)l, 16, 0, 0);
}

// ---------------- routing ----------------
__global__ void k_count(const int* __restrict__ se, int* __restrict__ counts) {
  int t = blockIdx.x * 256 + threadIdx.x;
  if (t >= T_TOK) return;
  int e0 = se[t * 2], e1 = se[t * 2 + 1];
  atomicAdd(&counts[e0], 1);
  if (e1 != e0) atomicAdd(&counts[e1], 1);
}

__global__ void k_offsets(const int* __restrict__ counts, int* __restrict__ padOff) {
  if (threadIdx.x == 0 && blockIdx.x == 0) {
    int acc = 0;
    for (int e = 0; e < E_NUM; e++) {
      padOff[e] = acc;
      acc += ((counts[e] + 127) / 128) * 128;
    }
    padOff[E_NUM] = acc;
  }
}

__global__ void k_fill(const int* __restrict__ se, const float* __restrict__ rw,
                       const int* __restrict__ padOff, int* __restrict__ cursor,
                       int* __restrict__ tokIdx, float* __restrict__ tokGate) {
  int t = blockIdx.x * 256 + threadIdx.x;
  if (t >= T_TOK) return;
  int e0 = se[t * 2], e1 = se[t * 2 + 1];
  float w0 = rw[t * 2], w1 = rw[t * 2 + 1];
  float g0 = w0 + (e1 == e0 ? w1 : 0.f);
  int s0 = atomicAdd(&cursor[e0], 1);
  tokIdx[padOff[e0] + s0] = t;
  tokGate[padOff[e0] + s0] = g0;
  if (e1 != e0) {
    int s1 = atomicAdd(&cursor[e1], 1);
    tokIdx[padOff[e1] + s1] = t;
    tokGate[padOff[e1] + s1] = w1;
  }
}

// ---------------- gather + quantize x ----------------
__global__ __launch_bounds__(256)
void k_gather(const float* __restrict__ x, const int* __restrict__ padOff,
              const int* __restrict__ counts, const int* __restrict__ tokIdx,
              const float* __restrict__ w1_is, unsigned short* __restrict__ xq) {
  const int rblk = blockIdx.x;
  const int total = padOff[E_NUM];
  if (rblk >= total) return;
  int e = 0;
  while (rblk >= padOff[e + 1]) e++;
  unsigned short* dst = xq + (size_t)rblk * H_DIM;
  const int c = threadIdx.x * 8;
  const int local = rblk - padOff[e];
  if (local >= counts[e]) {           // pad row -> zeros
    uint4 z = {0u, 0u, 0u, 0u};
    *(uint4*)(dst + c) = z;
    return;
  }
  const int tok = tokIdx[rblk];
  const float is = w1_is[e];
  const float* src = x + (size_t)tok * H_DIM + c;
  float4 v0 = *(const float4*)(src);
  float4 v1 = *(const float4*)(src + 4);
  float q0 = fp8_round(v0.x / is), q1 = fp8_round(v0.y / is);
  float q2 = fp8_round(v0.z / is), q3 = fp8_round(v0.w / is);
  float q4 = fp8_round(v1.x / is), q5 = fp8_round(v1.y / is);
  float q6 = fp8_round(v1.z / is), q7 = fp8_round(v1.w / is);
  uint4 o;
  o.x = (unsigned)bf16hi(q0) | ((unsigned)bf16hi(q1) << 16);
  o.y = (unsigned)bf16hi(q2) | ((unsigned)bf16hi(q3) << 16);
  o.z = (unsigned)bf16hi(q4) | ((unsigned)bf16hi(q5) << 16);
  o.w = (unsigned)bf16hi(q6) | ((unsigned)bf16hi(q7) << 16);
  *(uint4*)(dst + c) = o;
}

// ---------------- weight convert f32 -> bf16 (exact) ----------------
__global__ __launch_bounds__(256)
void k_wconv(const float* __restrict__ w, unsigned short* __restrict__ o, long n4) {
  long i = (long)blockIdx.x * 256 + threadIdx.x;
  if (i >= n4) return;
  float4 v = ((const float4*)w)[i];
  ushort4 r;
  r.x = bf16hi(v.x); r.y = bf16hi(v.y); r.z = bf16hi(v.z); r.w = bf16hi(v.w);
  ((ushort4*)o)[i] = r;
}

// ---------------- GEMM1: h = xq @ w1^T, fused silu*u + requant ----------------
// grid: (I/128, 32, E); block 512 (8 waves, wave tile 64x32, dual g/u accum)
__global__ __launch_bounds__(512, 1)
void k_gemm1(const unsigned short* __restrict__ xq,
             const unsigned short* __restrict__ w1b,
             const int* __restrict__ padOff,
             const float* __restrict__ w1_is, const float* __restrict__ w1_ws,
             const float* __restrict__ w2_is,
             unsigned short* __restrict__ aq) {
  const int e = blockIdx.z;
  const int rbase = padOff[e];
  const int rows = padOff[e + 1] - rbase;
  const int mt = blockIdx.y;
  if (mt * 128 >= rows) return;
  const int nt = blockIdx.x;

  __shared__ __align__(16) unsigned short As[128 * 32];
  __shared__ __align__(16) unsigned short Bg[128 * 32];
  __shared__ __align__(16) unsigned short Bu[128 * 32];

  const int tid = threadIdx.x;
  const int lane = tid & 63;
  const int wave = tid >> 6;
  const int wm = wave >> 2, wn = wave & 3;
  const int lr = lane & 15, quad = lane >> 4;

  const int r = tid >> 2;
  const int kb = tid & 3;
  const unsigned short* pa = xq + (size_t)(rbase + mt * 128 + r) * H_DIM + kb * 8;
  const unsigned short* pg = w1b + ((size_t)e * 2 * I_DIM + nt * 128 + r) * H_DIM + kb * 8;
  const unsigned short* pu = pg + (size_t)I_DIM * H_DIM;
  unsigned short* la = As + tid * 8;
  unsigned short* lg = Bg + tid * 8;
  unsigned short* lu = Bu + tid * 8;

  f32x4 accg[4][2] = {};
  f32x4 accu[4][2] = {};

  for (int k0 = 0; k0 < H_DIM; k0 += 32) {
    gld16(pa + k0, la);
    gld16(pg + k0, lg);
    gld16(pu + k0, lu);
    __syncthreads();
    bf16x8 af[4], gf[2], uf[2];
#pragma unroll
    for (int i = 0; i < 4; i++)
      af[i] = *(const bf16x8*)(As + (wm * 64 + i * 16 + lr) * 32 + quad * 8);
#pragma unroll
    for (int j = 0; j < 2; j++) {
      gf[j] = *(const bf16x8*)(Bg + (wn * 32 + j * 16 + lr) * 32 + quad * 8);
      uf[j] = *(const bf16x8*)(Bu + (wn * 32 + j * 16 + lr) * 32 + quad * 8);
    }
#pragma unroll
    for (int i = 0; i < 4; i++)
#pragma unroll
      for (int j = 0; j < 2; j++) {
        accg[i][j] = __builtin_amdgcn_mfma_f32_16x16x32_bf16(af[i], gf[j], accg[i][j], 0, 0, 0);
        accu[i][j] = __builtin_amdgcn_mfma_f32_16x16x32_bf16(af[i], uf[j], accu[i][j], 0, 0, 0);
      }
    __syncthreads();
  }

  const float s1 = w1_is[e] * w1_ws[e];
  const float is2 = w2_is[e];
#pragma unroll
  for (int i = 0; i < 4; i++)
#pragma unroll
    for (int j = 0; j < 2; j++)
#pragma unroll
      for (int rr = 0; rr < 4; rr++) {
        const int row = wm * 64 + i * 16 + quad * 4 + rr;
        const int col = nt * 128 + wn * 32 + j * 16 + lr;
        float g = accg[i][j][rr] * s1;
        float u = accu[i][j][rr] * s1;
        float a = (g / (1.f + expf(-g))) * u;   // silu(g)*u
        float q = fp8_round(a / is2);
        aq[(size_t)(rbase + mt * 128 + row) * I_DIM + col] = bf16hi(q);
      }
}

// ---------------- GEMM2: y = aq @ w2^T, scale*gate, scatter-add ----------------
// grid: (H/128, 32, E); block 512
__global__ __launch_bounds__(512, 1)
void k_gemm2(const unsigned short* __restrict__ aq,
             const unsigned short* __restrict__ w2b,
             const int* __restrict__ padOff, const int* __restrict__ counts,
             const int* __restrict__ tokIdx, const float* __restrict__ tokGate,
             const float* __restrict__ w2_is, const float* __restrict__ w2_ws,
             float* __restrict__ out) {
  const int e = blockIdx.z;
  const int rbase = padOff[e];
  const int rows = padOff[e + 1] - rbase;
  const int mt = blockIdx.y;
  if (mt * 128 >= rows) return;
  const int nt = blockIdx.x;
  const int cnt = counts[e];

  __shared__ __align__(16) unsigned short As[128 * 32];
  __shared__ __align__(16) unsigned short Bs[128 * 32];
  __shared__ int sTok[128];
  __shared__ float sGate[128];

  const int tid = threadIdx.x;
  const int lane = tid & 63;
  const int wave = tid >> 6;
  const int wm = wave >> 2, wn = wave & 3;
  const int lr = lane & 15, quad = lane >> 4;

  if (tid < 128) {
    int rr = mt * 128 + tid;
    if (rr < cnt) { sTok[tid] = tokIdx[rbase + rr]; sGate[tid] = tokGate[rbase + rr]; }
    else          { sTok[tid] = -1;                 sGate[tid] = 0.f; }
  }

  const int r = tid >> 2;
  const int kb = tid & 3;
  const unsigned short* pa = aq + (size_t)(rbase + mt * 128 + r) * I_DIM + kb * 8;
  const unsigned short* pb = w2b + ((size_t)e * H_DIM + nt * 128 + r) * I_DIM + kb * 8;
  unsigned short* la = As + tid * 8;
  unsigned short* lb = Bs + tid * 8;

  f32x4 acc[4][2] = {};

  for (int k0 = 0; k0 < I_DIM; k0 += 32) {
    gld16(pa + k0, la);
    gld16(pb + k0, lb);
    __syncthreads();
    bf16x8 af[4], bf[2];
#pragma unroll
    for (int i = 0; i < 4; i++)
      af[i] = *(const bf16x8*)(As + (wm * 64 + i * 16 + lr) * 32 + quad * 8);
#pragma unroll
    for (int j = 0; j < 2; j++)
      bf[j] = *(const bf16x8*)(Bs + (wn * 32 + j * 16 + lr) * 32 + quad * 8);
#pragma unroll
    for (int i = 0; i < 4; i++)
#pragma unroll
      for (int j = 0; j < 2; j++)
        acc[i][j] = __builtin_amdgcn_mfma_f32_16x16x32_bf16(af[i], bf[j], acc[i][j], 0, 0, 0);
    __syncthreads();
  }

  const float s2 = w2_is[e] * w2_ws[e];
#pragma unroll
  for (int i = 0; i < 4; i++)
#pragma unroll
    for (int j = 0; j < 2; j++)
#pragma unroll
      for (int rr = 0; rr < 4; rr++) {
        const int row = wm * 64 + i * 16 + quad * 4 + rr;
        const int tk = sTok[row];
        if (tk >= 0) {
          const int col = nt * 128 + wn * 32 + j * 16 + lr;
          unsafeAtomicAdd(out + (size_t)tk * H_DIM + col, sGate[row] * s2 * acc[i][j][rr]);
        }
      }
}

// ---------------- host launch ----------------
extern "C" void kernel_launch(void* const* d_in, const int* in_sizes, int n_in,
                              void* d_out, int out_size, void* d_ws, size_t ws_size,
                              hipStream_t stream) {
  const float* x     = (const float*)d_in[0];
  const int*   se    = (const int*)d_in[1];
  const float* rw    = (const float*)d_in[2];
  const float* w1    = (const float*)d_in[3];
  const float* w2    = (const float*)d_in[4];
  const float* w1_is = (const float*)d_in[5];
  const float* w2_is = (const float*)d_in[6];
  const float* w1_ws = (const float*)d_in[7];
  const float* w2_ws = (const float*)d_in[8];
  float* out = (float*)d_out;
  char* ws = (char*)d_ws;

  int*   counts  = (int*)(ws + OFF_COUNTS);
  int*   cursor  = (int*)(ws + OFF_CURSOR);
  int*   padOff  = (int*)(ws + OFF_PADOFF);
  int*   tokIdx  = (int*)(ws + OFF_TOKIDX);
  float* tokGate = (float*)(ws + OFF_TOKGATE);
  unsigned short* xq  = (unsigned short*)(ws + OFF_XQ);
  unsigned short* aq  = (unsigned short*)(ws + OFF_AQ);
  unsigned short* w1b = (unsigned short*)(ws + OFF_W1B);
  unsigned short* w2b = (unsigned short*)(ws + OFF_W2B);

  hipMemsetAsync(ws, 0, 1024, stream);
  hipMemsetAsync(d_out, 0, (size_t)T_TOK * H_DIM * sizeof(float), stream);

  k_count  <<<16, 256, 0, stream>>>(se, counts);
  k_offsets<<<1, 1, 0, stream>>>(counts, padOff);
  k_fill   <<<16, 256, 0, stream>>>(se, rw, padOff, cursor, tokIdx, tokGate);
  k_gather <<<CAP_ROWS, 256, 0, stream>>>(x, padOff, counts, tokIdx, w1_is, xq);

  k_wconv<<<131072, 256, 0, stream>>>(w1, w1b, (long)E_NUM * 2 * I_DIM * H_DIM / 4);
  k_wconv<<< 65536, 256, 0, stream>>>(w2, w2b, (long)E_NUM * H_DIM * I_DIM / 4);

  dim3 g1(I_DIM / 128, 32, E_NUM);
  k_gemm1<<<g1, 512, 0, stream>>>(xq, w1b, padOff, w1_is, w1_ws, w2_is, aq);

  dim3 g2(H_DIM / 128, 32, E_NUM);
  k_gemm2<<<g2, 512, 0, stream>>>(aq, w2b, padOff, counts, tokIdx, tokGate, w2_is, w2_ws, out);
}